// Round 1
// baseline (233.547 us; speedup 1.0000x reference)
//
#include <hip/hip_runtime.h>

// PCLLoss: C=256 classes, N=64 samples/class, D=1024.
// loss = mean_i [ sum_c ( log(eps + S_{i,c}) - pred[i,c] ) ]
// where pred = Mv Mv^T, true = Mt Mt^T, Mv/Mt = per-class means of
// L2-normalized rows, and S_{i,c} = sum_j exp(pred[i,j]) over j ranked
// at-or-after c in a stable descending sort of true[i,:].

#define CC 256
#define NN 64
#define DD 1024
#define PARTS 4          // partial class sums for occupancy

// ---------------- K1: partial sums of normalized rows -----------------
// grid = 2 * CC * PARTS = 2048 blocks, 256 threads (4 waves).
// Each wave handles 4 rows; lane l holds cols {k*256 + l*4 .. +3}, k=0..3.
__global__ __launch_bounds__(256) void k1_partial(
    const float* __restrict__ emb, const float* __restrict__ feat,
    float* __restrict__ parts /* [2][CC][PARTS][DD] */)
{
    int b = blockIdx.x;
    int t = b >> 10;              // tensor: 0=emb, 1=feat
    int c = (b >> 2) & 255;       // class
    int p = b & 3;                // part (16 rows)
    const float* src = (t == 0 ? emb : feat) + ((size_t)c * NN + p * 16) * DD;

    int wave = threadIdx.x >> 6;
    int lane = threadIdx.x & 63;

    float4 acc[4];
    #pragma unroll
    for (int k = 0; k < 4; ++k) acc[k] = make_float4(0.f, 0.f, 0.f, 0.f);

    #pragma unroll
    for (int j = 0; j < 4; ++j) {
        const float* row = src + (size_t)(wave * 4 + j) * DD;
        float4 v[4];
        #pragma unroll
        for (int k = 0; k < 4; ++k)
            v[k] = *(const float4*)(row + k * 256 + lane * 4);
        float ss = 0.f;
        #pragma unroll
        for (int k = 0; k < 4; ++k)
            ss += v[k].x * v[k].x + v[k].y * v[k].y + v[k].z * v[k].z + v[k].w * v[k].w;
        #pragma unroll
        for (int m = 32; m >= 1; m >>= 1)
            ss += __shfl_xor(ss, m, 64);
        float inv = 1.0f / fmaxf(sqrtf(ss), 1e-12f);  // F.normalize eps
        #pragma unroll
        for (int k = 0; k < 4; ++k) {
            acc[k].x += v[k].x * inv; acc[k].y += v[k].y * inv;
            acc[k].z += v[k].z * inv; acc[k].w += v[k].w * inv;
        }
    }

    // combine the 4 waves via LDS (one barrier)
    __shared__ float lds[4][DD];  // 16 KB
    #pragma unroll
    for (int k = 0; k < 4; ++k)
        *(float4*)&lds[wave][k * 256 + lane * 4] = acc[k];
    __syncthreads();

    int col = threadIdx.x * 4;
    float4 s = *(float4*)&lds[0][col];
    #pragma unroll
    for (int w = 1; w < 4; ++w) {
        float4 x = *(float4*)&lds[w][col];
        s.x += x.x; s.y += x.y; s.z += x.z; s.w += x.w;
    }
    float* dst = parts + (((size_t)t * CC + c) * PARTS + p) * DD + col;
    *(float4*)dst = s;
}

// ---------------- K2: combine partials -> class means -----------------
// grid = 2*CC = 512 blocks, 256 threads.
__global__ __launch_bounds__(256) void k2_combine(
    const float* __restrict__ parts, float* __restrict__ means /* [2][CC][DD] */)
{
    size_t base = (size_t)blockIdx.x * PARTS * DD;
    int col = threadIdx.x * 4;
    float4 s = *(const float4*)(parts + base + col);
    #pragma unroll
    for (int p = 1; p < PARTS; ++p) {
        float4 x = *(const float4*)(parts + base + (size_t)p * DD + col);
        s.x += x.x; s.y += x.y; s.z += x.z; s.w += x.w;
    }
    const float invN = 1.0f / (float)NN;
    s.x *= invN; s.y *= invN; s.z *= invN; s.w *= invN;
    *(float4*)(means + (size_t)blockIdx.x * DD + col) = s;
}

// ---------------- K3: Gram rows + sort-free ListMLE -------------------
// grid = CC blocks (row i), 256 threads (thread c = column).
__global__ __launch_bounds__(256) void k3_listmle(
    const float* __restrict__ means, float* __restrict__ row_loss)
{
    const float* mv = means;                    // [CC][DD]
    const float* mt = means + (size_t)CC * DD;  // [CC][DD]
    int i = blockIdx.x;
    int c = threadIdx.x;

    __shared__ float smv[DD];
    __shared__ float smt[DD];
    {
        int col = c * 4;
        *(float4*)&smv[col] = *(const float4*)(mv + (size_t)i * DD + col);
        *(float4*)&smt[col] = *(const float4*)(mt + (size_t)i * DD + col);
    }
    __syncthreads();

    const float* rv = mv + (size_t)c * DD;
    const float* rt = mt + (size_t)c * DD;
    float dp = 0.f, dt = 0.f;
    #pragma unroll 4
    for (int d = 0; d < DD; d += 4) {
        float4 a = *(const float4*)(rv + d);
        float4 b = *(const float4*)(rt + d);
        dp += a.x * smv[d] + a.y * smv[d + 1] + a.z * smv[d + 2] + a.w * smv[d + 3];
        dt += b.x * smt[d] + b.y * smt[d + 1] + b.z * smt[d + 2] + b.w * smt[d + 3];
    }

    __shared__ float s_true[CC];
    __shared__ float s_pexp[CC];
    s_true[c] = dt;
    s_pexp[c] = expf(dp);
    __syncthreads();

    // S = sum of exp(pred_j) over j ranked at-or-after c by stable desc sort of true
    float myt = dt;
    float S = 0.f;
    for (int j = 0; j < CC; ++j) {
        float tj = s_true[j];                               // LDS broadcast
        bool take = (tj < myt) || (tj == myt && j >= c);    // stable tie-break
        S += take ? s_pexp[j] : 0.f;
    }
    float contrib = logf(S + 1e-10f) - dp;

    #pragma unroll
    for (int m = 32; m >= 1; m >>= 1)
        contrib += __shfl_xor(contrib, m, 64);
    __shared__ float s_red[4];
    if ((c & 63) == 0) s_red[c >> 6] = contrib;
    __syncthreads();
    if (c == 0)
        row_loss[i] = s_red[0] + s_red[1] + s_red[2] + s_red[3];
}

// ---------------- K4: mean over rows ----------------------------------
__global__ __launch_bounds__(256) void k4_final(
    const float* __restrict__ row_loss, float* __restrict__ out)
{
    int tid = threadIdx.x;
    float v = row_loss[tid];
    #pragma unroll
    for (int m = 32; m >= 1; m >>= 1)
        v += __shfl_xor(v, m, 64);
    __shared__ float s[4];
    if ((tid & 63) == 0) s[tid >> 6] = v;
    __syncthreads();
    if (tid == 0) out[0] = (s[0] + s[1] + s[2] + s[3]) * (1.0f / (float)CC);
}

extern "C" void kernel_launch(void* const* d_in, const int* in_sizes, int n_in,
                              void* d_out, int out_size, void* d_ws, size_t ws_size,
                              hipStream_t stream) {
    const float* emb  = (const float*)d_in[0];
    const float* feat = (const float*)d_in[1];
    float* ws = (float*)d_ws;
    float* parts    = ws;                                   // 2*CC*PARTS*DD = 8 MiB
    float* means    = parts + (size_t)2 * CC * PARTS * DD;  // 2*CC*DD = 2 MiB
    float* row_loss = means + (size_t)2 * CC * DD;          // CC floats

    k1_partial<<<2 * CC * PARTS, 256, 0, stream>>>(emb, feat, parts);
    k2_combine<<<2 * CC, 256, 0, stream>>>(parts, means);
    k3_listmle<<<CC, 256, 0, stream>>>(means, row_loss);
    k4_final<<<1, 256, 0, stream>>>(row_loss, (float*)d_out);
}

// Round 2
// 200.735 us; speedup vs baseline: 1.1635x; 1.1635x over previous
//
#include <hip/hip_runtime.h>

// PCLLoss: C=256 classes, N=64 samples/class, D=1024.
// loss = mean_i [ sum_c ( log(eps + S_{i,c}) - pred[i,c] ) ]
// pred = Mv Mv^T, true = Mt Mt^T, Mv/Mt = per-class means of L2-normalized
// rows; S_{i,c} = sum_j exp(pred[i,j]) over j ranked at-or-after c in a
// stable descending sort of true[i,:]  (computed sort-free via an O(C) scan).

#define CC 256
#define NN 64
#define DD 1024
#define PARTS 4
#define TK 128   // K-slice for gram split-K

// ---------------- K1a: inverse norms of all 2*C*N rows ----------------
// grid = 8192 blocks x 256 thr; one wave per row; all loads independent.
__global__ __launch_bounds__(256) void k1a_norms(
    const float* __restrict__ emb, const float* __restrict__ feat,
    float* __restrict__ inv_norm /* [2*CC*NN] */)
{
    int wave = threadIdx.x >> 6, lane = threadIdx.x & 63;
    int row = blockIdx.x * 4 + wave;  // 0 .. 2*CC*NN-1
    const float* src = (row < CC * NN) ? emb + (size_t)row * DD
                                       : feat + (size_t)(row - CC * NN) * DD;
    float4 v[4];
    #pragma unroll
    for (int k = 0; k < 4; ++k)
        v[k] = *(const float4*)(src + k * 256 + lane * 4);
    float ss = 0.f;
    #pragma unroll
    for (int k = 0; k < 4; ++k)
        ss += v[k].x * v[k].x + v[k].y * v[k].y + v[k].z * v[k].z + v[k].w * v[k].w;
    #pragma unroll
    for (int m = 32; m >= 1; m >>= 1)
        ss += __shfl_xor(ss, m, 64);
    if (lane == 0)
        inv_norm[row] = 1.0f / fmaxf(sqrtf(ss), 1e-12f);  // F.normalize eps
}

// ---------------- K1b: scale rows by inv_norm, partial class sums -----
// grid = 2*CC*PARTS = 2048 blocks; wave handles 4 rows, loads all independent.
__global__ __launch_bounds__(256) void k1b_partial(
    const float* __restrict__ emb, const float* __restrict__ feat,
    const float* __restrict__ inv_norm,
    float* __restrict__ parts /* [2][CC][PARTS][DD] */)
{
    int b = blockIdx.x;
    int t = b >> 10;              // tensor
    int c = (b >> 2) & 255;       // class
    int p = b & 3;                // part (16 rows)
    const float* src = (t == 0 ? emb : feat) + ((size_t)c * NN + p * 16) * DD;
    const float* inv = inv_norm + ((size_t)t * CC + c) * NN + p * 16;

    int wave = threadIdx.x >> 6, lane = threadIdx.x & 63;

    float4 v[4][4];
    #pragma unroll
    for (int j = 0; j < 4; ++j) {
        const float* row = src + (size_t)(wave * 4 + j) * DD;
        #pragma unroll
        for (int k = 0; k < 4; ++k)
            v[j][k] = *(const float4*)(row + k * 256 + lane * 4);
    }
    float4 iv = *(const float4*)(inv + wave * 4);
    float invj[4] = {iv.x, iv.y, iv.z, iv.w};

    float4 acc[4];
    #pragma unroll
    for (int k = 0; k < 4; ++k) acc[k] = make_float4(0.f, 0.f, 0.f, 0.f);
    #pragma unroll
    for (int j = 0; j < 4; ++j) {
        #pragma unroll
        for (int k = 0; k < 4; ++k) {
            acc[k].x += v[j][k].x * invj[j]; acc[k].y += v[j][k].y * invj[j];
            acc[k].z += v[j][k].z * invj[j]; acc[k].w += v[j][k].w * invj[j];
        }
    }

    __shared__ float lds[4][DD];  // 16 KB
    #pragma unroll
    for (int k = 0; k < 4; ++k)
        *(float4*)&lds[wave][k * 256 + lane * 4] = acc[k];
    __syncthreads();

    int col = threadIdx.x * 4;
    float4 s = *(float4*)&lds[0][col];
    #pragma unroll
    for (int w = 1; w < 4; ++w) {
        float4 x = *(float4*)&lds[w][col];
        s.x += x.x; s.y += x.y; s.z += x.z; s.w += x.w;
    }
    *(float4*)(parts + (((size_t)t * CC + c) * PARTS + p) * DD + col) = s;
}

// ---------------- K2: combine partials -> class means -----------------
__global__ __launch_bounds__(256) void k2_combine(
    const float* __restrict__ parts, float* __restrict__ means /* [2][CC][DD] */)
{
    size_t base = (size_t)blockIdx.x * PARTS * DD;
    int col = threadIdx.x * 4;
    float4 s = *(const float4*)(parts + base + col);
    #pragma unroll
    for (int p = 1; p < PARTS; ++p) {
        float4 x = *(const float4*)(parts + base + (size_t)p * DD + col);
        s.x += x.x; s.y += x.y; s.z += x.z; s.w += x.w;
    }
    const float invN = 1.0f / (float)NN;
    s.x *= invN; s.y *= invN; s.z *= invN; s.w *= invN;
    *(float4*)(means + (size_t)blockIdx.x * DD + col) = s;
}

// ---------------- K3a: split-K tiled Gram partials --------------------
// grid = 2 tensors * 16 tiles(64x64) * 8 K-splits = 256 blocks, 256 thr.
// A natural [64][132]; B transposed [TK][68]; 4x4 microtile per thread.
__global__ __launch_bounds__(256) void k3a_gram(
    const float* __restrict__ means, float* __restrict__ gpart /* [2][8][CC][CC] */)
{
    __shared__ float As[64][132];  // pad 132: b128-aligned rows, low conflicts
    __shared__ float Bs[TK][68];   // pad 68: b128-aligned rows

    int b = blockIdx.x;
    int t = b >> 7;
    int r = b & 127;
    int ks = r >> 4;
    int ti = (r >> 2) & 3, tj = r & 3;
    int i0 = ti * 64, j0 = tj * 64, k0 = ks * TK;
    const float* M = means + (size_t)t * CC * DD;

    // stage A: rows i0.., cols k0..k0+127 (coalesced, contiguous LDS writes)
    for (int f = threadIdx.x; f < 64 * 32; f += 256) {
        int row = f >> 5, c4 = f & 31;
        float4 v = *(const float4*)(M + (size_t)(i0 + row) * DD + k0 + c4 * 4);
        *(float4*)&As[row][c4 * 4] = v;
    }
    // stage B transposed: Bs[k][j]
    for (int f = threadIdx.x; f < 64 * 32; f += 256) {
        int row = f >> 5, c4 = f & 31;
        float4 v = *(const float4*)(M + (size_t)(j0 + row) * DD + k0 + c4 * 4);
        Bs[c4 * 4 + 0][row] = v.x;
        Bs[c4 * 4 + 1][row] = v.y;
        Bs[c4 * 4 + 2][row] = v.z;
        Bs[c4 * 4 + 3][row] = v.w;
    }
    __syncthreads();

    int tr = threadIdx.x >> 4, tc = threadIdx.x & 15;
    float acc[4][4] = {};
    #pragma unroll 4
    for (int kk = 0; kk < TK; kk += 4) {
        float4 a[4], bb[4];
        #pragma unroll
        for (int q = 0; q < 4; ++q) a[q] = *(float4*)&As[tr * 4 + q][kk];
        #pragma unroll
        for (int kq = 0; kq < 4; ++kq) bb[kq] = *(float4*)&Bs[kk + kq][tc * 4];
        #pragma unroll
        for (int q = 0; q < 4; ++q) {
            acc[q][0] += a[q].x * bb[0].x + a[q].y * bb[1].x + a[q].z * bb[2].x + a[q].w * bb[3].x;
            acc[q][1] += a[q].x * bb[0].y + a[q].y * bb[1].y + a[q].z * bb[2].y + a[q].w * bb[3].y;
            acc[q][2] += a[q].x * bb[0].z + a[q].y * bb[1].z + a[q].z * bb[2].z + a[q].w * bb[3].z;
            acc[q][3] += a[q].x * bb[0].w + a[q].y * bb[1].w + a[q].z * bb[2].w + a[q].w * bb[3].w;
        }
    }

    float* G = gpart + (((size_t)(t * 8 + ks) * CC) + i0 + tr * 4) * CC + j0 + tc * 4;
    #pragma unroll
    for (int q = 0; q < 4; ++q)
        *(float4*)(G + (size_t)q * CC) =
            make_float4(acc[q][0], acc[q][1], acc[q][2], acc[q][3]);
}

// ---------------- K3b: reduce partials + sort-free ListMLE ------------
__global__ __launch_bounds__(256) void k3b_listmle(
    const float* __restrict__ gpart, float* __restrict__ row_loss)
{
    int i = blockIdx.x, c = threadIdx.x;
    float dp = 0.f, dt = 0.f;
    #pragma unroll
    for (int ks = 0; ks < 8; ++ks) {
        dp += gpart[((size_t)ks * CC + i) * CC + c];
        dt += gpart[((size_t)(8 + ks) * CC + i) * CC + c];
    }

    __shared__ float s_true[CC];
    __shared__ float s_pexp[CC];
    s_true[c] = dt;
    s_pexp[c] = expf(dp);
    __syncthreads();

    // S = sum exp(pred_j) over j ranked at-or-after c (stable desc by true)
    float S = 0.f;
    for (int j = 0; j < CC; ++j) {
        float tj = s_true[j];
        bool take = (tj < dt) || (tj == dt && j >= c);
        S += take ? s_pexp[j] : 0.f;
    }
    float contrib = logf(S + 1e-10f) - dp;

    #pragma unroll
    for (int m = 32; m >= 1; m >>= 1)
        contrib += __shfl_xor(contrib, m, 64);
    __shared__ float s_red[4];
    if ((c & 63) == 0) s_red[c >> 6] = contrib;
    __syncthreads();
    if (c == 0)
        row_loss[i] = s_red[0] + s_red[1] + s_red[2] + s_red[3];
}

// ---------------- K4: mean over rows ----------------------------------
__global__ __launch_bounds__(256) void k4_final(
    const float* __restrict__ row_loss, float* __restrict__ out)
{
    int tid = threadIdx.x;
    float v = row_loss[tid];
    #pragma unroll
    for (int m = 32; m >= 1; m >>= 1)
        v += __shfl_xor(v, m, 64);
    __shared__ float s[4];
    if ((tid & 63) == 0) s[tid >> 6] = v;
    __syncthreads();
    if (tid == 0) out[0] = (s[0] + s[1] + s[2] + s[3]) * (1.0f / (float)CC);
}

extern "C" void kernel_launch(void* const* d_in, const int* in_sizes, int n_in,
                              void* d_out, int out_size, void* d_ws, size_t ws_size,
                              hipStream_t stream) {
    const float* emb  = (const float*)d_in[0];
    const float* feat = (const float*)d_in[1];
    float* ws = (float*)d_ws;
    float* parts    = ws;                                   // 8 MiB
    float* means    = parts + (size_t)2 * CC * PARTS * DD;  // 2 MiB
    float* inv_norm = means + (size_t)2 * CC * DD;          // 128 KiB
    float* row_loss = inv_norm + (size_t)2 * CC * NN;       // 1 KiB
    float* gpart    = parts;  // reuse: parts consumed by k2 before k3a runs

    k1a_norms  <<<2 * CC * NN / 4, 256, 0, stream>>>(emb, feat, inv_norm);
    k1b_partial<<<2 * CC * PARTS, 256, 0, stream>>>(emb, feat, inv_norm, parts);
    k2_combine <<<2 * CC, 256, 0, stream>>>(parts, means);
    k3a_gram   <<<256, 256, 0, stream>>>(means, gpart);
    k3b_listmle<<<CC, 256, 0, stream>>>(gpart, row_loss);
    k4_final   <<<1, 256, 0, stream>>>(row_loss, (float*)d_out);
}

// Round 3
// 184.838 us; speedup vs baseline: 1.2635x; 1.0860x over previous
//
#include <hip/hip_runtime.h>

// PCLLoss: C=256 classes, N=64 samples/class, D=1024.
// loss = mean_i [ sum_c ( log(eps + S_{i,c}) - pred[i,c] ) ]
// pred = Mv Mv^T, true = Mt Mt^T, Mv/Mt = per-class means of L2-normalized
// rows; S_{i,c} = sum_j exp(pred[i,j]) over j ranked at-or-after c in a
// stable descending sort of true[i,:]  (computed sort-free via an O(C) scan).
//
// R3: single-read fused k1 (norm + class-mean in one pass, 512 blocks writing
// means directly — R2's two-pass k1a/k1b read the 128 MiB input twice and was
// a hidden regression). k4 fused into k3b via one atomicAdd per block.

#define CC 256
#define NN 64
#define DD 1024
#define TK 128   // K-slice for gram split-K

// ---------------- K1: fused normalize + class means -------------------
// grid = 2*CC = 512 blocks x 256 thr. Block (t,c); wave handles 16 rows in
// 4 batches of 4; the 4 shuffle-reductions per batch are interleaved (ILP).
__global__ __launch_bounds__(256) void k1_means(
    const float* __restrict__ emb, const float* __restrict__ feat,
    float* __restrict__ means /* [2][CC][DD] */, float* __restrict__ out)
{
    if (blockIdx.x == 0 && threadIdx.x == 0) out[0] = 0.f;  // for k3b atomics

    int t = blockIdx.x >> 8;
    int c = blockIdx.x & 255;
    const float* src = (t == 0 ? emb : feat) + (size_t)c * NN * DD;
    int wave = threadIdx.x >> 6, lane = threadIdx.x & 63;

    float4 acc[4];
    #pragma unroll
    for (int k = 0; k < 4; ++k) acc[k] = make_float4(0.f, 0.f, 0.f, 0.f);

    for (int batch = 0; batch < 4; ++batch) {
        const float* base = src + (size_t)(wave * 16 + batch * 4) * DD;
        float4 v[4][4];
        #pragma unroll
        for (int j = 0; j < 4; ++j)
            #pragma unroll
            for (int k = 0; k < 4; ++k)
                v[j][k] = *(const float4*)(base + (size_t)j * DD + k * 256 + lane * 4);

        float ss[4];
        #pragma unroll
        for (int j = 0; j < 4; ++j) {
            ss[j] = 0.f;
            #pragma unroll
            for (int k = 0; k < 4; ++k)
                ss[j] += v[j][k].x * v[j][k].x + v[j][k].y * v[j][k].y +
                         v[j][k].z * v[j][k].z + v[j][k].w * v[j][k].w;
        }
        // 4 independent butterfly reductions, interleaved
        #pragma unroll
        for (int m = 32; m >= 1; m >>= 1) {
            #pragma unroll
            for (int j = 0; j < 4; ++j)
                ss[j] += __shfl_xor(ss[j], m, 64);
        }
        #pragma unroll
        for (int j = 0; j < 4; ++j) {
            float inv = 1.0f / fmaxf(sqrtf(ss[j]), 1e-12f);  // F.normalize eps
            #pragma unroll
            for (int k = 0; k < 4; ++k) {
                acc[k].x += v[j][k].x * inv; acc[k].y += v[j][k].y * inv;
                acc[k].z += v[j][k].z * inv; acc[k].w += v[j][k].w * inv;
            }
        }
    }

    // combine the 4 waves via LDS, divide by N, write means
    __shared__ float lds[4][DD];  // 16 KB
    #pragma unroll
    for (int k = 0; k < 4; ++k)
        *(float4*)&lds[wave][k * 256 + lane * 4] = acc[k];
    __syncthreads();

    int col = threadIdx.x * 4;
    float4 s = *(float4*)&lds[0][col];
    #pragma unroll
    for (int w = 1; w < 4; ++w) {
        float4 x = *(float4*)&lds[w][col];
        s.x += x.x; s.y += x.y; s.z += x.z; s.w += x.w;
    }
    const float invN = 1.0f / (float)NN;
    s.x *= invN; s.y *= invN; s.z *= invN; s.w *= invN;
    *(float4*)(means + (size_t)blockIdx.x * DD + col) = s;
}

// ---------------- K3a: split-K tiled Gram partials --------------------
// grid = 2 tensors * 16 tiles(64x64) * 8 K-splits = 256 blocks, 256 thr.
__global__ __launch_bounds__(256) void k3a_gram(
    const float* __restrict__ means, float* __restrict__ gpart /* [2][8][CC][CC] */)
{
    __shared__ float As[64][132];
    __shared__ float Bs[TK][68];

    int b = blockIdx.x;
    int t = b >> 7;
    int r = b & 127;
    int ks = r >> 4;
    int ti = (r >> 2) & 3, tj = r & 3;
    int i0 = ti * 64, j0 = tj * 64, k0 = ks * TK;
    const float* M = means + (size_t)t * CC * DD;

    for (int f = threadIdx.x; f < 64 * 32; f += 256) {
        int row = f >> 5, c4 = f & 31;
        float4 v = *(const float4*)(M + (size_t)(i0 + row) * DD + k0 + c4 * 4);
        *(float4*)&As[row][c4 * 4] = v;
    }
    for (int f = threadIdx.x; f < 64 * 32; f += 256) {
        int row = f >> 5, c4 = f & 31;
        float4 v = *(const float4*)(M + (size_t)(j0 + row) * DD + k0 + c4 * 4);
        Bs[c4 * 4 + 0][row] = v.x;
        Bs[c4 * 4 + 1][row] = v.y;
        Bs[c4 * 4 + 2][row] = v.z;
        Bs[c4 * 4 + 3][row] = v.w;
    }
    __syncthreads();

    int tr = threadIdx.x >> 4, tc = threadIdx.x & 15;
    float acc[4][4] = {};
    #pragma unroll 4
    for (int kk = 0; kk < TK; kk += 4) {
        float4 a[4], bb[4];
        #pragma unroll
        for (int q = 0; q < 4; ++q) a[q] = *(float4*)&As[tr * 4 + q][kk];
        #pragma unroll
        for (int kq = 0; kq < 4; ++kq) bb[kq] = *(float4*)&Bs[kk + kq][tc * 4];
        #pragma unroll
        for (int q = 0; q < 4; ++q) {
            acc[q][0] += a[q].x * bb[0].x + a[q].y * bb[1].x + a[q].z * bb[2].x + a[q].w * bb[3].x;
            acc[q][1] += a[q].x * bb[0].y + a[q].y * bb[1].y + a[q].z * bb[2].y + a[q].w * bb[3].y;
            acc[q][2] += a[q].x * bb[0].z + a[q].y * bb[1].z + a[q].z * bb[2].z + a[q].w * bb[3].z;
            acc[q][3] += a[q].x * bb[0].w + a[q].y * bb[1].w + a[q].z * bb[2].w + a[q].w * bb[3].w;
        }
    }

    float* G = gpart + (((size_t)(t * 8 + ks) * CC) + i0 + tr * 4) * CC + j0 + tc * 4;
    #pragma unroll
    for (int q = 0; q < 4; ++q)
        *(float4*)(G + (size_t)q * CC) =
            make_float4(acc[q][0], acc[q][1], acc[q][2], acc[q][3]);
}

// ---------------- K3b: reduce partials + ListMLE + final mean ---------
// grid = CC blocks; one atomicAdd per block into out (zeroed by k1).
__global__ __launch_bounds__(256) void k3b_listmle(
    const float* __restrict__ gpart, float* __restrict__ out)
{
    int i = blockIdx.x, c = threadIdx.x;
    float dp = 0.f, dt = 0.f;
    #pragma unroll
    for (int ks = 0; ks < 8; ++ks) {
        dp += gpart[((size_t)ks * CC + i) * CC + c];
        dt += gpart[((size_t)(8 + ks) * CC + i) * CC + c];
    }

    __shared__ float s_true[CC];
    __shared__ float s_pexp[CC];
    s_true[c] = dt;
    s_pexp[c] = expf(dp);
    __syncthreads();

    // S = sum exp(pred_j) over j ranked at-or-after c (stable desc by true)
    float S = 0.f;
    for (int j = 0; j < CC; ++j) {
        float tj = s_true[j];
        bool take = (tj < dt) || (tj == dt && j >= c);
        S += take ? s_pexp[j] : 0.f;
    }
    float contrib = logf(S + 1e-10f) - dp;

    #pragma unroll
    for (int m = 32; m >= 1; m >>= 1)
        contrib += __shfl_xor(contrib, m, 64);
    __shared__ float s_red[4];
    if ((c & 63) == 0) s_red[c >> 6] = contrib;
    __syncthreads();
    if (c == 0)
        atomicAdd(out, (s_red[0] + s_red[1] + s_red[2] + s_red[3]) * (1.0f / (float)CC));
}

extern "C" void kernel_launch(void* const* d_in, const int* in_sizes, int n_in,
                              void* d_out, int out_size, void* d_ws, size_t ws_size,
                              hipStream_t stream) {
    const float* emb  = (const float*)d_in[0];
    const float* feat = (const float*)d_in[1];
    float* ws = (float*)d_ws;
    float* means = ws;                                // 2*CC*DD   = 2 MiB
    float* gpart = means + (size_t)2 * CC * DD;       // 2*8*CC*CC = 4 MiB

    k1_means   <<<2 * CC, 256, 0, stream>>>(emb, feat, means, (float*)d_out);
    k3a_gram   <<<256, 256, 0, stream>>>(means, gpart);
    k3b_listmle<<<CC, 256, 0, stream>>>(gpart, (float*)d_out);
}